// Round 6
// baseline (451.460 us; speedup 1.0000x reference)
//
#include <hip/hip_runtime.h>
#include <cstdint>

#define BB 4
#define NN 2048
#define KK 32
#define CC 128
#define C0 128
#define C2 256
#define CIN0 259
#define RW 160                 // pre-transposed row width (128 feat | 3 pos | 29 zero)
#define EPSF 1e-5f
#define SLOPE 0.01f

// ---- ws layout (float offsets unless noted) ----
#define PAR0 0
#define PAR1 256
#define PAR2 512                          // -> 1024
#define R1OFF 1024                        // 64x512 -> 33792
#define MAXOFF 33792                      // 8192x256
#define MINOFF (MAXOFF + 2097152)
#define PART (MINOFF + 2097152)           // 8192x512 per-WAVE partial stats rows
#define PART_END (PART + 4194304)
#define T2_USH (PART_END * 2)             // ushort offset; BB*NN*160 ush
#define T1_USH (T2_USH + BB*NN*RW)
#define WP_USH (T1_USH + BB*NN*RW)        // packed W: 176*512 ush  (~39 MB total)

// packed-W frags: L0: 8 mt x 10 ck = 80; L1: 8x4=32; L2: 16x4=64
#define NFRAG0 80
#define NFRAG1 32
#define NFRAG2 64

typedef float floatx4 __attribute__((ext_vector_type(4)));
typedef short shortx8 __attribute__((ext_vector_type(8)));

#define MFMA16(A,B,C) __builtin_amdgcn_mfma_f32_16x16x32_bf16((A),(B),(C),0,0,0)

__device__ __forceinline__ ushort f2bf(float f) {
    union { float f; uint u; } v; v.f = f;
    uint r = (v.u + 0x7fffu + ((v.u >> 16) & 1u)) >> 16;
    return (ushort)r;
}

// XOR-swizzled address into a wave-private [32 k][128 ch] bf16 slice (pitch 256B).
// ch2 = channel byte offset (ch*2). Swizzle spreads rows across 16B slots.
__device__ __forceinline__ void* hsw(ushort* Hw, int k, int ch2) {
    return (void*)((char*)Hw + k * 256 + (ch2 ^ ((k & 7) << 4)));
}

// feat[b][C][N] f32 + pos[b][3][N] f32 -> dst[b][n][160] bf16 rows:
// cols 0-127 feat, 128-130 sign*pos, 131-159 zero
__global__ __launch_bounds__(256) void transpose_fp(const float* __restrict__ feat,
                                                    const float* __restrict__ pos,
                                                    float sign, ushort* __restrict__ dst) {
    __shared__ __align__(16) ushort Ts[32][168];
    int b = blockIdx.x >> 6, n0 = (blockIdx.x & 63) * 32;
    int t = threadIdx.x;
#pragma unroll
    for (int i = 0; i < 16; i++) {
        int c = i * 8 + (t >> 5);
        Ts[t & 31][c] = f2bf(feat[((size_t)b * CC + c) * NN + n0 + (t & 31)]);
    }
    if (t < 96) {
        int c = t >> 5, k = t & 31;
        Ts[k][128 + c] = f2bf(sign * pos[((size_t)b * 3 + c) * NN + n0 + k]);
    }
    if (t < 32) {
        for (int c = 131; c < RW; c++) Ts[t][c] = 0;
    }
    __syncthreads();
    int n = t >> 3, q = t & 7;
    ushort* drow = dst + ((size_t)b * NN + n0 + n) * RW;
    *(uint4*)&drow[q * 16]     = *(const uint4*)&Ts[n][q * 16];
    *(uint4*)&drow[q * 16 + 8] = *(const uint4*)&Ts[n][q * 16 + 8];
    if (q < 4) *(uint4*)&drow[128 + q * 8] = *(const uint4*)&Ts[n][128 + q * 8];
}

// Pack W into bf16 MFMA A-fragment order. L0 has 10 cin-chunks:
// ck 0-4 gather side: c<128 -> W0[o][3+c]; c 128-130 -> W0[o][c-128]; else 0
// ck 5-9 broadcast side: c<128 -> W0[o][131+c]; c 128-130 -> W0[o][c-128]; else 0
__global__ __launch_bounds__(256) void pack_w(const float* __restrict__ W0,
                                              const float* __restrict__ W1,
                                              const float* __restrict__ W2,
                                              short* __restrict__ wp0) {
    int tid = blockIdx.x * 256 + threadIdx.x;   // 176*64 = 11264
    int fid = tid >> 6, lane = tid & 63, g = (lane >> 4) & 3, lcol = lane & 15;
    short* wp1 = wp0 + NFRAG0 * 512;
    short* wp2 = wp1 + NFRAG1 * 512;
    ushort v[8];
    short* dst;
    if (fid < NFRAG0) {
        int mt = fid / 10, ck = fid % 10, o = mt * 16 + lcol;
        const float* wrow = W0 + (size_t)o * CIN0;
        int gather = (ck < 5);
        int cbase = (gather ? ck : ck - 5) * 32 + g * 8;
#pragma unroll
        for (int i = 0; i < 8; i++) {
            int c = cbase + i;
            float x;
            if (c < 128)      x = gather ? wrow[3 + c] : wrow[131 + c];
            else if (c < 131) x = wrow[c - 128];
            else              x = 0.f;
            v[i] = f2bf(x);
        }
        dst = wp0 + ((size_t)fid * 64 + lane) * 8;
    } else if (fid < NFRAG0 + NFRAG1) {
        int f = fid - NFRAG0, mt = f / 4, ck = f % 4, o = mt * 16 + lcol;
#pragma unroll
        for (int i = 0; i < 8; i++) v[i] = f2bf(W1[(size_t)o * C0 + ck * 32 + g * 8 + i]);
        dst = wp1 + ((size_t)f * 64 + lane) * 8;
    } else {
        int f = fid - NFRAG0 - NFRAG1, mt = f / 4, ck = f % 4, o = mt * 16 + lcol;
#pragma unroll
        for (int i = 0; i < 8; i++) v[i] = f2bf(W2[(size_t)o * C0 + ck * 32 + g * 8 + i]);
        dst = wp2 + ((size_t)f * 64 + lane) * 8;
    }
#pragma unroll
    for (int i = 0; i < 8; i++) dst[i] = (short)v[i];
}

// Per-wave stats row: acc[m][nt][r] = y[ch=(mtbase+m)*16+g*4+r][k=nt*16+lcol].
// Writes sum at [PART + pid*512 + ch], sumsq at +sqoff.
template<int NM>
__device__ __forceinline__ void stats_row(const floatx4 (&acc)[NM][2], int mtbase,
                                          int g, int lcol, int pid, int sqoff,
                                          float* __restrict__ ws) {
#pragma unroll
    for (int m = 0; m < NM; m++) {
        floatx4 s = {}, q = {};
#pragma unroll
        for (int r = 0; r < 4; r++) {
            float a0 = acc[m][0][r], a1 = acc[m][1][r];
            float ss = a0 + a1, qq = a0 * a0 + a1 * a1;
#pragma unroll
            for (int d = 1; d < 16; d <<= 1) { ss += __shfl_xor(ss, d); qq += __shfl_xor(qq, d); }
            s[r] = ss; q[r] = qq;
        }
        if (lcol == 0) {
            int ch = (mtbase + m) * 16 + g * 4;
            *(floatx4*)&ws[PART + (size_t)pid * 512 + ch] = s;
            *(floatx4*)&ws[PART + (size_t)pid * 512 + sqoff + ch] = q;
        }
    }
}

// BN+lrelu on an 8-mt acc block, bf16, into the wave-private swizzled H slice.
__device__ __forceinline__ void bn_h(const floatx4 (&acc)[8][2], int g, int lcol,
                                     int paroff, const float* __restrict__ ws,
                                     ushort* Hw) {
#pragma unroll
    for (int mt = 0; mt < 8; mt++) {
        int ch = mt * 16 + g * 4;
        floatx4 sc = *(const floatx4*)&ws[paroff + ch];
        floatx4 sh = *(const floatx4*)&ws[paroff + 128 + ch];
#pragma unroll
        for (int nt = 0; nt < 2; nt++) {
            int k = nt * 16 + lcol;
            ushort h[4];
#pragma unroll
            for (int r = 0; r < 4; r++) {
                float z = fmaf(acc[mt][nt][r], sc[r], sh[r]);
                z = fmaxf(z, SLOPE * z);           // leaky-relu
                h[r] = f2bf(z);
            }
            uint2 val;
            val.x = (uint)h[0] | ((uint)h[1] << 16);
            val.y = (uint)h[2] | ((uint)h[3] << 16);
            *(uint2*)hsw(Hw, k, mt * 32 + g * 8) = val;
        }
    }
}

// One WAVE = one point. No __syncthreads anywhere; H slices are wave-private.
template<int NL>
__global__ __launch_bounds__(256, (NL == 3 ? 3 : 4)) void pass_kernel(
    const ushort* __restrict__ T2x, const ushort* __restrict__ T1x,
    const int* __restrict__ idxg, const short* __restrict__ wp0,
    float* __restrict__ ws)
{
    const int t = threadIdx.x;
    const int wave = t >> 6, lane = t & 63, g = lane >> 4, lcol = lane & 15;
    const int pid = blockIdx.x * 4 + wave;
    const int b = pid >> 11, n = pid & (NN - 1);
    const shortx8* wf0 = (const shortx8*)wp0;
    const shortx8* wf1 = wf0 + NFRAG0 * 64;
    const shortx8* wf2 = wf1 + NFRAG1 * 64;

    const int j0 = idxg[pid * KK + lcol];
    const int j1 = idxg[pid * KK + 16 + lcol];
    const ushort* r0 = T2x + ((size_t)(b * NN + j0)) * RW;
    const ushort* r1 = T2x + ((size_t)(b * NN + j1)) * RW;
    const ushort* fr = T1x + ((size_t)(b * NN + n)) * RW;

    // ---- layer 0 (wave computes all 8 M-tiles for its own point) ----
    floatx4 acc[8][2] = {};
#pragma unroll
    for (int ck = 0; ck < 5; ck++) {               // gather chunks
        shortx8 B0 = *(const shortx8*)(r0 + ck * 32 + g * 8);
        shortx8 B1 = *(const shortx8*)(r1 + ck * 32 + g * 8);
#pragma unroll
        for (int mt = 0; mt < 8; mt++) {
            shortx8 A = wf0[(mt * 10 + ck) * 64 + lane];
            acc[mt][0] = MFMA16(A, B0, acc[mt][0]);
            acc[mt][1] = MFMA16(A, B1, acc[mt][1]);
        }
    }
#pragma unroll
    for (int ck = 0; ck < 5; ck++) {               // broadcast chunks (f1 | -pos1)
        shortx8 F = *(const shortx8*)(fr + ck * 32 + g * 8);
#pragma unroll
        for (int mt = 0; mt < 8; mt++) {
            shortx8 A = wf0[(mt * 10 + 5 + ck) * 64 + lane];
            acc[mt][0] = MFMA16(A, F, acc[mt][0]);
            acc[mt][1] = MFMA16(A, F, acc[mt][1]);
        }
    }

    if constexpr (NL == 1) {
        stats_row<8>(acc, 0, g, lcol, pid, 128, ws);
    } else {
        __shared__ __align__(16) ushort Hall[4][4096];   // 8KB private slice per wave
        ushort* Hw = &Hall[wave][0];

        bn_h(acc, g, lcol, PAR0, ws, Hw);
        __builtin_amdgcn_wave_barrier();           // keep LDS write->read order

        // ---- layer 1 ----
        floatx4 acc1[8][2] = {};
#pragma unroll
        for (int ck = 0; ck < 4; ck++) {
            shortx8 B0 = *(const shortx8*)hsw(Hw, lcol,      ck * 64 + g * 16);
            shortx8 B1 = *(const shortx8*)hsw(Hw, lcol + 16, ck * 64 + g * 16);
#pragma unroll
            for (int mt = 0; mt < 8; mt++) {
                shortx8 A = wf1[(mt * 4 + ck) * 64 + lane];
                acc1[mt][0] = MFMA16(A, B0, acc1[mt][0]);
                acc1[mt][1] = MFMA16(A, B1, acc1[mt][1]);
            }
        }

        if constexpr (NL == 2) {
            stats_row<8>(acc1, 0, g, lcol, pid, 128, ws);
        } else {
            __builtin_amdgcn_wave_barrier();       // all L1 reads done before overwrite
            bn_h(acc1, g, lcol, PAR1, ws, Hw);
            __builtin_amdgcn_wave_barrier();

            // ---- layer 2: 16 M-tiles in 4 quarters (VGPR control) ----
#pragma unroll
            for (int mq = 0; mq < 4; mq++) {
                floatx4 a2[4][2] = {};
#pragma unroll
                for (int ck = 0; ck < 4; ck++) {
                    shortx8 B0 = *(const shortx8*)hsw(Hw, lcol,      ck * 64 + g * 16);
                    shortx8 B1 = *(const shortx8*)hsw(Hw, lcol + 16, ck * 64 + g * 16);
#pragma unroll
                    for (int m = 0; m < 4; m++) {
                        shortx8 A = wf2[((mq * 4 + m) * 4 + ck) * 64 + lane];
                        a2[m][0] = MFMA16(A, B0, a2[m][0]);
                        a2[m][1] = MFMA16(A, B1, a2[m][1]);
                    }
                }
                stats_row<4>(a2, mq * 4, g, lcol, pid, 256, ws);
                // per-point max/min over k
#pragma unroll
                for (int m = 0; m < 4; m++) {
                    floatx4 mx, mn;
#pragma unroll
                    for (int r = 0; r < 4; r++) {
                        mx[r] = fmaxf(a2[m][0][r], a2[m][1][r]);
                        mn[r] = fminf(a2[m][0][r], a2[m][1][r]);
                    }
#pragma unroll
                    for (int d = 1; d < 16; d <<= 1) {
#pragma unroll
                        for (int r = 0; r < 4; r++) {
                            mx[r] = fmaxf(mx[r], __shfl_xor(mx[r], d));
                            mn[r] = fminf(mn[r], __shfl_xor(mn[r], d));
                        }
                    }
                    if (lcol == 0) {
                        int ch = (mq * 4 + m) * 16 + g * 4;
                        *(floatx4*)&ws[MAXOFF + (size_t)pid * C2 + ch] = mx;
                        *(floatx4*)&ws[MINOFF + (size_t)pid * C2 + ch] = mn;
                    }
                }
            }
        }
    }
}

// level-1 reduction: 8192 partial rows (pitch 512) -> 64 rows
__global__ __launch_bounds__(256) void reduce1(float* __restrict__ ws, int srcoff,
                                               int rows_per_block, int ncol) {
    int j = blockIdx.x, t = threadIdx.x;
    const float* base = ws + srcoff + (size_t)j * rows_per_block * 512;
    float a0 = 0.f, a1 = 0.f;
    for (int i = 0; i < rows_per_block; i++) {
        a0 += base[(size_t)i * 512 + t];
        if (ncol > 256) a1 += base[(size_t)i * 512 + 256 + t];
    }
    ws[R1OFF + (size_t)j * 512 + t] = a0;
    if (ncol > 256) ws[R1OFF + (size_t)j * 512 + 256 + t] = a1;
}

__global__ void finalize(const float* __restrict__ g, const float* __restrict__ bparm,
                         float* __restrict__ ws, int CL, int paroff) {
    int ch = threadIdx.x;
    if (ch >= CL) return;
    float s = 0.f, s2 = 0.f;
    for (int j = 0; j < 64; j++) {
        s  += ws[R1OFF + (size_t)j * 512 + ch];
        s2 += ws[R1OFF + (size_t)j * 512 + CL + ch];
    }
    const float inv = 1.0f / ((float)BB * NN * KK);
    float mean = s * inv, var = s2 * inv - mean * mean;
    float sc = g[ch] * rsqrtf(var + EPSF);
    ws[paroff + ch] = sc;
    ws[paroff + CL + ch] = bparm[ch] - mean * sc;
}

// out = lrelu(scale*(scale>=0?max:min)+shift), transposed through LDS
__global__ __launch_bounds__(256) void out_kernel(const float* __restrict__ ws,
                                                  float* __restrict__ out) {
    __shared__ float T[32][261];
    int blk = blockIdx.x;                  // 256 blocks
    int b = blk >> 6, n0 = (blk & 63) * 32;
    int t = threadIdx.x;
    float s = ws[PAR2 + t], sh = ws[PAR2 + C2 + t];
    const float* Mx = ws + MAXOFF;
    const float* Mn = ws + MINOFF;
    for (int r = 0; r < 32; r++) {
        size_t base = ((size_t)(b * NN + n0 + r)) * C2 + t;
        float v = (s >= 0.f) ? Mx[base] : Mn[base];
        float z = fmaf(v, s, sh);
        T[r][t] = z >= 0.f ? z : SLOPE * z;
    }
    __syncthreads();
    float* o2 = out + BB * 3 * NN;
    int c = t & 31, og = t >> 5;
    for (int ss = 0; ss < 32; ss++) {
        int o = og * 32 + ss;
        o2[((size_t)(b * C2 + o)) * NN + n0 + c] = T[c][o];
    }
}

extern "C" void kernel_launch(void* const* d_in, const int* in_sizes, int n_in,
                              void* d_out, int out_size, void* d_ws, size_t ws_size,
                              hipStream_t stream) {
    const float* pos1 = (const float*)d_in[0];
    const float* pos2 = (const float*)d_in[1];
    const float* f1   = (const float*)d_in[2];
    const float* f2   = (const float*)d_in[3];
    const int*   idx  = (const int*)d_in[4];
    const float* W0 = (const float*)d_in[5];
    const float* g0 = (const float*)d_in[6];
    const float* b0 = (const float*)d_in[7];
    const float* W1 = (const float*)d_in[8];
    const float* g1 = (const float*)d_in[9];
    const float* b1 = (const float*)d_in[10];
    const float* W2 = (const float*)d_in[11];
    const float* g2 = (const float*)d_in[12];
    const float* b2 = (const float*)d_in[13];
    float* ws  = (float*)d_ws;
    float* out = (float*)d_out;
    ushort* wsu = (ushort*)d_ws;
    ushort* T2p = wsu + T2_USH;
    ushort* T1p = wsu + T1_USH;
    short* wp0  = (short*)(wsu + WP_USH);

    // output 0: pos1 passthrough
    hipMemcpyAsync(d_out, d_in[0], (size_t)BB * 3 * NN * sizeof(float),
                   hipMemcpyDeviceToDevice, stream);

    transpose_fp<<<BB * 64, 256, 0, stream>>>(f2, pos2,  1.0f, T2p);
    transpose_fp<<<BB * 64, 256, 0, stream>>>(f1, pos1, -1.0f, T1p);
    pack_w<<<(NFRAG0 + NFRAG1 + NFRAG2) * 64 / 256, 256, 0, stream>>>(W0, W1, W2, wp0);

    pass_kernel<1><<<BB * NN / 4, 256, 0, stream>>>(T2p, T1p, idx, wp0, ws);
    reduce1<<<64, 256, 0, stream>>>(ws, PART, 128, 256);
    finalize<<<1, 256, 0, stream>>>(g0, b0, ws, C0, PAR0);

    pass_kernel<2><<<BB * NN / 4, 256, 0, stream>>>(T2p, T1p, idx, wp0, ws);
    reduce1<<<64, 256, 0, stream>>>(ws, PART, 128, 256);
    finalize<<<1, 256, 0, stream>>>(g1, b1, ws, C0, PAR1);

    pass_kernel<3><<<BB * NN / 4, 256, 0, stream>>>(T2p, T1p, idx, wp0, ws);
    reduce1<<<64, 256, 0, stream>>>(ws, PART, 128, 512);
    finalize<<<1, 256, 0, stream>>>(g2, b2, ws, C2, PAR2);

    out_kernel<<<BB * (NN / 32), 256, 0, stream>>>(ws, out);
}

// Round 7
// 319.329 us; speedup vs baseline: 1.4138x; 1.4138x over previous
//
#include <hip/hip_runtime.h>
#include <cstdint>

#define BB 4
#define NN 2048
#define KK 32
#define CC 128
#define C0 128
#define C2 256
#define CIN0 259
#define RW 160                 // pre-transposed row width (128 feat | 3 pos | 29 zero)
#define EPSF 1e-5f
#define SLOPE 0.01f

// ---- ws layout (float offsets unless noted) ----
#define PAR0 0
#define PAR1 256
#define PAR2 512                          // -> 1024
#define R1OFF 1024                        // 64x512 -> 33792
#define MAXOFF 33792                      // 8192x256
#define MINOFF (MAXOFF + 2097152)
#define PART   (MINOFF + 2097152)         // A/B: 8192 rows x256 ; C: 2048 rows x512
#define Y0_USH ((PART + 2097152) * 2)     // ushort offset; 8192x4096 ush (64MB)
#define T2_USH (Y0_USH + 33554432)
#define T1_USH (T2_USH + BB*NN*RW)
#define WP_USH (T1_USH + BB*NN*RW)        // packed W: 176*512 ush  (~93 MB total)

// packed-W frags: L0: 8 mt x 10 ck = 80; L1: 8x4=32; L2: 16x4=64
#define NFRAG0 80
#define NFRAG1 32
#define NFRAG2 64

typedef float floatx4 __attribute__((ext_vector_type(4)));
typedef short shortx8 __attribute__((ext_vector_type(8)));

#define MFMA16(A,B,C) __builtin_amdgcn_mfma_f32_16x16x32_bf16((A),(B),(C),0,0,0)

__device__ __forceinline__ ushort f2bf(float f) {
    union { float f; uint u; } v; v.f = f;
    uint r = (v.u + 0x7fffu + ((v.u >> 16) & 1u)) >> 16;
    return (ushort)r;
}

// feat[b][C][N] f32 + pos[b][3][N] f32 -> dst[b][n][160] bf16 rows:
// cols 0-127 feat, 128-130 sign*pos, 131-159 zero
__global__ __launch_bounds__(256) void transpose_fp(const float* __restrict__ feat,
                                                    const float* __restrict__ pos,
                                                    float sign, ushort* __restrict__ dst) {
    __shared__ __align__(16) ushort Ts[32][168];
    int b = blockIdx.x >> 6, n0 = (blockIdx.x & 63) * 32;
    int t = threadIdx.x;
#pragma unroll
    for (int i = 0; i < 16; i++) {
        int c = i * 8 + (t >> 5);
        Ts[t & 31][c] = f2bf(feat[((size_t)b * CC + c) * NN + n0 + (t & 31)]);
    }
    if (t < 96) {
        int c = t >> 5, k = t & 31;
        Ts[k][128 + c] = f2bf(sign * pos[((size_t)b * 3 + c) * NN + n0 + k]);
    }
    if (t < 32) {
        for (int c = 131; c < RW; c++) Ts[t][c] = 0;
    }
    __syncthreads();
    int n = t >> 3, q = t & 7;
    ushort* drow = dst + ((size_t)b * NN + n0 + n) * RW;
    *(uint4*)&drow[q * 16]     = *(const uint4*)&Ts[n][q * 16];
    *(uint4*)&drow[q * 16 + 8] = *(const uint4*)&Ts[n][q * 16 + 8];
    if (q < 4) *(uint4*)&drow[128 + q * 8] = *(const uint4*)&Ts[n][128 + q * 8];
}

// Pack W into bf16 MFMA A-fragment order. L0 has 10 cin-chunks:
// ck 0-4 gather side: c<128 -> W0[o][3+c]; c 128-130 -> W0[o][c-128]; else 0
// ck 5-9 broadcast side: c<128 -> W0[o][131+c]; c 128-130 -> W0[o][c-128]; else 0
__global__ __launch_bounds__(256) void pack_w(const float* __restrict__ W0,
                                              const float* __restrict__ W1,
                                              const float* __restrict__ W2,
                                              short* __restrict__ wp0) {
    int tid = blockIdx.x * 256 + threadIdx.x;   // 176*64 = 11264
    int fid = tid >> 6, lane = tid & 63, g = (lane >> 4) & 3, lcol = lane & 15;
    short* wp1 = wp0 + NFRAG0 * 512;
    short* wp2 = wp1 + NFRAG1 * 512;
    ushort v[8];
    short* dst;
    if (fid < NFRAG0) {
        int mt = fid / 10, ck = fid % 10, o = mt * 16 + lcol;
        const float* wrow = W0 + (size_t)o * CIN0;
        int gather = (ck < 5);
        int cbase = (gather ? ck : ck - 5) * 32 + g * 8;
#pragma unroll
        for (int i = 0; i < 8; i++) {
            int c = cbase + i;
            float x;
            if (c < 128)      x = gather ? wrow[3 + c] : wrow[131 + c];
            else if (c < 131) x = wrow[c - 128];
            else              x = 0.f;
            v[i] = f2bf(x);
        }
        dst = wp0 + ((size_t)fid * 64 + lane) * 8;
    } else if (fid < NFRAG0 + NFRAG1) {
        int f = fid - NFRAG0, mt = f / 4, ck = f % 4, o = mt * 16 + lcol;
#pragma unroll
        for (int i = 0; i < 8; i++) v[i] = f2bf(W1[(size_t)o * C0 + ck * 32 + g * 8 + i]);
        dst = wp1 + ((size_t)f * 64 + lane) * 8;
    } else {
        int f = fid - NFRAG0 - NFRAG1, mt = f / 4, ck = f % 4, o = mt * 16 + lcol;
#pragma unroll
        for (int i = 0; i < 8; i++) v[i] = f2bf(W2[(size_t)o * C0 + ck * 32 + g * 8 + i]);
        dst = wp2 + ((size_t)f * 64 + lane) * 8;
    }
#pragma unroll
    for (int i = 0; i < 8; i++) dst[i] = (short)v[i];
}

// per-wave 128-ch stats row, pitch 256: [sum128|sq128]
__device__ __forceinline__ void stats_row256(const floatx4 (&acc)[8][2], int g, int lcol,
                                             int pid, float* __restrict__ ws) {
#pragma unroll
    for (int m = 0; m < 8; m++) {
        floatx4 s, q;
#pragma unroll
        for (int r = 0; r < 4; r++) {
            float a0 = acc[m][0][r], a1 = acc[m][1][r];
            float ss = a0 + a1, qq = a0 * a0 + a1 * a1;
#pragma unroll
            for (int d = 1; d < 16; d <<= 1) { ss += __shfl_xor(ss, d); qq += __shfl_xor(qq, d); }
            s[r] = ss; q[r] = qq;
        }
        if (lcol == 0) {
            int ch = m * 16 + g * 4;
            *(floatx4*)&ws[PART + (size_t)pid * 256 + ch] = s;
            *(floatx4*)&ws[PART + (size_t)pid * 256 + 128 + ch] = q;
        }
    }
}

// ---- pass A: L0 once, store raw y0 bf16 [pid][k][128] + stats0 rows ----
__global__ __launch_bounds__(256, 4) void pass_A(
    const ushort* __restrict__ T2x, const ushort* __restrict__ T1x,
    const int* __restrict__ idxg, const short* __restrict__ wp0,
    float* __restrict__ ws, ushort* __restrict__ y0)
{
    const int t = threadIdx.x;
    const int wave = t >> 6, lane = t & 63, g = lane >> 4, lcol = lane & 15;
    const int pid = blockIdx.x * 4 + wave;
    const int b = pid >> 11, n = pid & (NN - 1);
    const shortx8* wf0 = (const shortx8*)wp0;
    const int j0 = idxg[pid * KK + lcol];
    const int j1 = idxg[pid * KK + 16 + lcol];
    const ushort* r0 = T2x + ((size_t)(b * NN + j0)) * RW;
    const ushort* r1 = T2x + ((size_t)(b * NN + j1)) * RW;
    const ushort* fr = T1x + ((size_t)(b * NN + n)) * RW;

    floatx4 acc[8][2] = {};
#pragma unroll
    for (int ck = 0; ck < 5; ck++) {               // gather chunks
        shortx8 B0 = *(const shortx8*)(r0 + ck * 32 + g * 8);
        shortx8 B1 = *(const shortx8*)(r1 + ck * 32 + g * 8);
#pragma unroll
        for (int mt = 0; mt < 8; mt++) {
            shortx8 A = wf0[(mt * 10 + ck) * 64 + lane];
            acc[mt][0] = MFMA16(A, B0, acc[mt][0]);
            acc[mt][1] = MFMA16(A, B1, acc[mt][1]);
        }
    }
#pragma unroll
    for (int ck = 0; ck < 5; ck++) {               // broadcast chunks (f1 | -pos1)
        shortx8 F = *(const shortx8*)(fr + ck * 32 + g * 8);
#pragma unroll
        for (int mt = 0; mt < 8; mt++) {
            shortx8 A = wf0[(mt * 10 + 5 + ck) * 64 + lane];
            acc[mt][0] = MFMA16(A, F, acc[mt][0]);
            acc[mt][1] = MFMA16(A, F, acc[mt][1]);
        }
    }
    // scatter-store y0: the global round trip IS the C->B transpose
    ushort* yr = y0 + (size_t)pid * 4096;
#pragma unroll
    for (int nt = 0; nt < 2; nt++) {
        int k = nt * 16 + lcol;
#pragma unroll
        for (int mt = 0; mt < 8; mt++) {
            uint2 v;
            v.x = (uint)f2bf(acc[mt][nt][0]) | ((uint)f2bf(acc[mt][nt][1]) << 16);
            v.y = (uint)f2bf(acc[mt][nt][2]) | ((uint)f2bf(acc[mt][nt][3]) << 16);
            *(uint2*)(yr + k * 128 + mt * 16 + g * 4) = v;
        }
    }
    stats_row256(acc, g, lcol, pid, ws);
}

// shared: read y0 row, BN0+lrelu in-register, L1 GEMM -> acc1 (C-layout)
__device__ __forceinline__ void l1_from_y0(const ushort* __restrict__ yr,
                                           const float* __restrict__ ws,
                                           const shortx8* __restrict__ wf1,
                                           int lane, int g, int lcol,
                                           floatx4 (&acc1)[8][2])
{
#pragma unroll
    for (int ck = 0; ck < 4; ck++) {
        int chb = ck * 32 + g * 8;
        floatx4 scA = *(const floatx4*)&ws[PAR0 + chb];
        floatx4 scB = *(const floatx4*)&ws[PAR0 + chb + 4];
        floatx4 shA = *(const floatx4*)&ws[PAR0 + 128 + chb];
        floatx4 shB = *(const floatx4*)&ws[PAR0 + 128 + chb + 4];
        shortx8 raw0 = *(const shortx8*)(yr + lcol * 128 + chb);
        shortx8 raw1 = *(const shortx8*)(yr + (lcol + 16) * 128 + chb);
        shortx8 B0, B1;
#pragma unroll
        for (int i = 0; i < 8; i++) {
            float sc = (i < 4) ? scA[i] : scB[i - 4];
            float sh = (i < 4) ? shA[i] : shB[i - 4];
            union { uint u; float f; } c0, c1;
            c0.u = ((uint)(ushort)raw0[i]) << 16;
            c1.u = ((uint)(ushort)raw1[i]) << 16;
            float z0 = fmaf(c0.f, sc, sh); z0 = fmaxf(z0, SLOPE * z0);
            float z1 = fmaf(c1.f, sc, sh); z1 = fmaxf(z1, SLOPE * z1);
            B0[i] = (short)f2bf(z0);
            B1[i] = (short)f2bf(z1);
        }
#pragma unroll
        for (int mt = 0; mt < 8; mt++) {
            shortx8 A = wf1[(mt * 4 + ck) * 64 + lane];
            acc1[mt][0] = MFMA16(A, B0, acc1[mt][0]);
            acc1[mt][1] = MFMA16(A, B1, acc1[mt][1]);
        }
    }
}

// ---- pass B: y0 -> BN0 -> L1 -> stats1 rows. No LDS, no barriers. ----
__global__ __launch_bounds__(256, 4) void pass_B(const ushort* __restrict__ y0,
                                                 const short* __restrict__ wp0,
                                                 float* __restrict__ ws)
{
    const int t = threadIdx.x;
    const int wave = t >> 6, lane = t & 63, g = lane >> 4, lcol = lane & 15;
    const int pid = blockIdx.x * 4 + wave;
    const shortx8* wf1 = (const shortx8*)wp0 + NFRAG0 * 64;
    floatx4 acc1[8][2] = {};
    l1_from_y0(y0 + (size_t)pid * 4096, ws, wf1, lane, g, lcol, acc1);
    stats_row256(acc1, g, lcol, pid, ws);
}

// ---- pass C: y0 -> BN0 -> L1 -> BN1 -> H(LDS) -> L2 (M-split) -> stats2 + maxmin ----
__global__ __launch_bounds__(256, 3) void pass_C(const ushort* __restrict__ y0,
                                                 const short* __restrict__ wp0,
                                                 float* __restrict__ ws)
{
    __shared__ __align__(16) ushort H[4][32][136];
    const int t = threadIdx.x;
    const int wave = t >> 6, lane = t & 63, g = lane >> 4, lcol = lane & 15;
    const int bid = blockIdx.x, pid0 = bid * 4, pid = pid0 + wave;
    const shortx8* wf1 = (const shortx8*)wp0 + NFRAG0 * 64;
    const shortx8* wf2 = wf1 + NFRAG1 * 64;

    floatx4 acc1[8][2] = {};
    l1_from_y0(y0 + (size_t)pid * 4096, ws, wf1, lane, g, lcol, acc1);

    // BN1 + lrelu -> H[wave][k][ch]
#pragma unroll
    for (int mt = 0; mt < 8; mt++) {
        int ch = mt * 16 + g * 4;
        floatx4 sc = *(const floatx4*)&ws[PAR1 + ch];
        floatx4 sh = *(const floatx4*)&ws[PAR1 + 128 + ch];
#pragma unroll
        for (int nt = 0; nt < 2; nt++) {
            ushort h[4];
#pragma unroll
            for (int r = 0; r < 4; r++) {
                float z = fmaf(acc1[mt][nt][r], sc[r], sh[r]);
                z = fmaxf(z, SLOPE * z);
                h[r] = f2bf(z);
            }
            uint2 v;
            v.x = (uint)h[0] | ((uint)h[1] << 16);
            v.y = (uint)h[2] | ((uint)h[3] << 16);
            *(uint2*)&H[wave][nt * 16 + lcol][ch] = v;
        }
    }
    __syncthreads();

    // L2: wave owns mt-slice wave*4..+3 for all 4 points (A-frags amortized 4x)
    floatx4 s[4] = {}, q[4] = {};
#pragma unroll
    for (int p = 0; p < 4; p++) {
        floatx4 a2[4][2] = {};
#pragma unroll
        for (int ck = 0; ck < 4; ck++) {
            shortx8 B0 = *(const shortx8*)&H[p][lcol][ck * 32 + g * 8];
            shortx8 B1 = *(const shortx8*)&H[p][lcol + 16][ck * 32 + g * 8];
#pragma unroll
            for (int m = 0; m < 4; m++) {
                shortx8 A = wf2[((wave * 4 + m) * 4 + ck) * 64 + lane];
                a2[m][0] = MFMA16(A, B0, a2[m][0]);
                a2[m][1] = MFMA16(A, B1, a2[m][1]);
            }
        }
#pragma unroll
        for (int m = 0; m < 4; m++) {
            floatx4 mx, mn;
#pragma unroll
            for (int r = 0; r < 4; r++) {
                float a0 = a2[m][0][r], a1 = a2[m][1][r];
                s[m][r] += a0 + a1;
                q[m][r] += a0 * a0 + a1 * a1;
                mx[r] = fmaxf(a0, a1);
                mn[r] = fminf(a0, a1);
            }
#pragma unroll
            for (int d = 1; d < 16; d <<= 1) {
#pragma unroll
                for (int r = 0; r < 4; r++) {
                    mx[r] = fmaxf(mx[r], __shfl_xor(mx[r], d));
                    mn[r] = fminf(mn[r], __shfl_xor(mn[r], d));
                }
            }
            if (lcol == 0) {
                int ch = wave * 64 + m * 16 + g * 4;
                *(floatx4*)&ws[MAXOFF + (size_t)(pid0 + p) * C2 + ch] = mx;
                *(floatx4*)&ws[MINOFF + (size_t)(pid0 + p) * C2 + ch] = mn;
            }
        }
    }
    // per-block stats row (pitch 512): waves write disjoint 64-ch slices
#pragma unroll
    for (int m = 0; m < 4; m++) {
#pragma unroll
        for (int r = 0; r < 4; r++) {
            float ss = s[m][r], qq = q[m][r];
#pragma unroll
            for (int d = 1; d < 16; d <<= 1) { ss += __shfl_xor(ss, d); qq += __shfl_xor(qq, d); }
            s[m][r] = ss; q[m][r] = qq;
        }
        if (lcol == 0) {
            int ch = wave * 64 + m * 16 + g * 4;
            *(floatx4*)&ws[PART + (size_t)bid * 512 + ch] = s[m];
            *(floatx4*)&ws[PART + (size_t)bid * 512 + 256 + ch] = q[m];
        }
    }
}

// level-1 reduction of partial rows -> 64 rows at R1OFF (pitch 512)
__global__ __launch_bounds__(256) void reduce1(float* __restrict__ ws, int srcoff,
                                               int rpb, int pitch, int ncol) {
    int j = blockIdx.x, t = threadIdx.x;
    const float* base = ws + srcoff + (size_t)j * rpb * pitch;
    float a0 = 0.f, a1 = 0.f;
    for (int i = 0; i < rpb; i++) {
        a0 += base[(size_t)i * pitch + t];
        if (ncol > 256) a1 += base[(size_t)i * pitch + 256 + t];
    }
    ws[R1OFF + (size_t)j * 512 + t] = a0;
    if (ncol > 256) ws[R1OFF + (size_t)j * 512 + 256 + t] = a1;
}

__global__ void finalize(const float* __restrict__ g, const float* __restrict__ bparm,
                         float* __restrict__ ws, int CL, int paroff) {
    int ch = threadIdx.x;
    if (ch >= CL) return;
    float s = 0.f, s2 = 0.f;
    for (int j = 0; j < 64; j++) {
        s  += ws[R1OFF + (size_t)j * 512 + ch];
        s2 += ws[R1OFF + (size_t)j * 512 + CL + ch];
    }
    const float inv = 1.0f / ((float)BB * NN * KK);
    float mean = s * inv, var = s2 * inv - mean * mean;
    float sc = g[ch] * rsqrtf(var + EPSF);
    ws[paroff + ch] = sc;
    ws[paroff + CL + ch] = bparm[ch] - mean * sc;
}

// out = lrelu(scale*(scale>=0?max:min)+shift), transposed through LDS
__global__ __launch_bounds__(256) void out_kernel(const float* __restrict__ ws,
                                                  float* __restrict__ out) {
    __shared__ float T[32][261];
    int blk = blockIdx.x;                  // 256 blocks
    int b = blk >> 6, n0 = (blk & 63) * 32;
    int t = threadIdx.x;
    float s = ws[PAR2 + t], sh = ws[PAR2 + C2 + t];
    const float* Mx = ws + MAXOFF;
    const float* Mn = ws + MINOFF;
    for (int r = 0; r < 32; r++) {
        size_t base = ((size_t)(b * NN + n0 + r)) * C2 + t;
        float v = (s >= 0.f) ? Mx[base] : Mn[base];
        float z = fmaf(v, s, sh);
        T[r][t] = z >= 0.f ? z : SLOPE * z;
    }
    __syncthreads();
    float* o2 = out + BB * 3 * NN;
    int c = t & 31, og = t >> 5;
    for (int ss = 0; ss < 32; ss++) {
        int o = og * 32 + ss;
        o2[((size_t)(b * C2 + o)) * NN + n0 + c] = T[c][o];
    }
}

extern "C" void kernel_launch(void* const* d_in, const int* in_sizes, int n_in,
                              void* d_out, int out_size, void* d_ws, size_t ws_size,
                              hipStream_t stream) {
    const float* pos1 = (const float*)d_in[0];
    const float* pos2 = (const float*)d_in[1];
    const float* f1   = (const float*)d_in[2];
    const float* f2   = (const float*)d_in[3];
    const int*   idx  = (const int*)d_in[4];
    const float* W0 = (const float*)d_in[5];
    const float* g0 = (const float*)d_in[6];
    const float* b0 = (const float*)d_in[7];
    const float* W1 = (const float*)d_in[8];
    const float* g1 = (const float*)d_in[9];
    const float* b1 = (const float*)d_in[10];
    const float* W2 = (const float*)d_in[11];
    const float* g2 = (const float*)d_in[12];
    const float* b2 = (const float*)d_in[13];
    float* ws  = (float*)d_ws;
    float* out = (float*)d_out;
    ushort* wsu = (ushort*)d_ws;
    ushort* y0p = wsu + Y0_USH;
    ushort* T2p = wsu + T2_USH;
    ushort* T1p = wsu + T1_USH;
    short* wp0  = (short*)(wsu + WP_USH);

    // output 0: pos1 passthrough
    hipMemcpyAsync(d_out, d_in[0], (size_t)BB * 3 * NN * sizeof(float),
                   hipMemcpyDeviceToDevice, stream);

    transpose_fp<<<BB * 64, 256, 0, stream>>>(f2, pos2,  1.0f, T2p);
    transpose_fp<<<BB * 64, 256, 0, stream>>>(f1, pos1, -1.0f, T1p);
    pack_w<<<(NFRAG0 + NFRAG1 + NFRAG2) * 64 / 256, 256, 0, stream>>>(W0, W1, W2, wp0);

    pass_A<<<BB * NN / 4, 256, 0, stream>>>(T2p, T1p, idx, wp0, ws, y0p);
    reduce1<<<64, 256, 0, stream>>>(ws, PART, 128, 256, 256);
    finalize<<<1, 256, 0, stream>>>(g0, b0, ws, C0, PAR0);

    pass_B<<<BB * NN / 4, 256, 0, stream>>>(y0p, wp0, ws);
    reduce1<<<64, 256, 0, stream>>>(ws, PART, 128, 256, 256);
    finalize<<<1, 256, 0, stream>>>(g1, b1, ws, C0, PAR1);

    pass_C<<<BB * NN / 4, 256, 0, stream>>>(y0p, wp0, ws);
    reduce1<<<64, 256, 0, stream>>>(ws, PART, 32, 512, 512);
    finalize<<<1, 256, 0, stream>>>(g2, b2, ws, C2, PAR2);

    out_kernel<<<BB * (NN / 32), 256, 0, stream>>>(ws, out);
}